// Round 1
// baseline (100.045 us; speedup 1.0000x reference)
//
#include <hip/hip_runtime.h>

// 2D RoPE: x (B=8, H=16, N=4096, C=128) fp32.
// R = 32. Quarters: x0=[0:32), x1=[32:64), x2=[64:96), x3=[96:128).
// y0 = x0*rcos - x1*rsin ; y1 = x0*rsin + x1*rcos   (row tables)
// y2 = x2*ccos - x3*csin ; y3 = x2*csin + x3*ccos   (col tables)
// row_cs/col_cs: (64, 32, 2) fp32, [..,0]=cos, [..,1]=sin.

#define NPOS 4096           // GRID_H * GRID_W
#define F4_PER_ROW 32       // 128 floats / 4

__global__ __launch_bounds__(256)
void rope2d_kernel(const float4* __restrict__ x,
                   const int*    __restrict__ idx,
                   const float4* __restrict__ row_cs,   // per pos: 16 float4 (64 floats)
                   const float4* __restrict__ col_cs,
                   float4*       __restrict__ out,
                   long long total)                      // work items = rows * 8
{
    const long long stride = (long long)gridDim.x * blockDim.x;
    for (long long g = (long long)blockIdx.x * blockDim.x + threadIdx.x;
         g < total; g += stride) {
        const long long rowid = g >> 3;         // which (b,h,n) row
        const int t = (int)(g & 7);             // float4 lane within quarter [0,8)
        const int n = (int)(rowid & (NPOS - 1));

        const int id   = idx[n];
        const int prow = id >> 16;
        const int pcol = id & 0xffff;

        const long long base = rowid * F4_PER_ROW;

        const float4 x0 = x[base + t];
        const float4 x1 = x[base + t + 8];
        const float4 x2 = x[base + t + 16];
        const float4 x3 = x[base + t + 24];

        // channel group r = t*4 .. t*4+3
        // rcs0 = (cos r, sin r, cos r+1, sin r+1), rcs1 = (cos r+2, sin r+2, cos r+3, sin r+3)
        const float4 rcs0 = row_cs[prow * 16 + t * 2];
        const float4 rcs1 = row_cs[prow * 16 + t * 2 + 1];
        const float4 ccs0 = col_cs[pcol * 16 + t * 2];
        const float4 ccs1 = col_cs[pcol * 16 + t * 2 + 1];

        float4 y0, y1, y2, y3;
        y0.x = x0.x * rcs0.x - x1.x * rcs0.y;   y1.x = x0.x * rcs0.y + x1.x * rcs0.x;
        y0.y = x0.y * rcs0.z - x1.y * rcs0.w;   y1.y = x0.y * rcs0.w + x1.y * rcs0.z;
        y0.z = x0.z * rcs1.x - x1.z * rcs1.y;   y1.z = x0.z * rcs1.y + x1.z * rcs1.x;
        y0.w = x0.w * rcs1.z - x1.w * rcs1.w;   y1.w = x0.w * rcs1.w + x1.w * rcs1.z;

        y2.x = x2.x * ccs0.x - x3.x * ccs0.y;   y3.x = x2.x * ccs0.y + x3.x * ccs0.x;
        y2.y = x2.y * ccs0.z - x3.y * ccs0.w;   y3.y = x2.y * ccs0.w + x3.y * ccs0.z;
        y2.z = x2.z * ccs1.x - x3.z * ccs1.y;   y3.z = x2.z * ccs1.y + x3.z * ccs1.x;
        y2.w = x2.w * ccs1.z - x3.w * ccs1.w;   y3.w = x2.w * ccs1.w + x3.w * ccs1.z;

        out[base + t]      = y0;
        out[base + t + 8]  = y1;
        out[base + t + 16] = y2;
        out[base + t + 24] = y3;
    }
}

extern "C" void kernel_launch(void* const* d_in, const int* in_sizes, int n_in,
                              void* d_out, int out_size, void* d_ws, size_t ws_size,
                              hipStream_t stream) {
    const float4* x      = (const float4*)d_in[0];
    const int*    idx    = (const int*)d_in[1];
    const float4* row_cs = (const float4*)d_in[2];
    const float4* col_cs = (const float4*)d_in[3];
    float4*       out    = (float4*)d_out;

    // each work item processes 16 floats (4 x float4)
    const long long total = (long long)in_sizes[0] / 16;

    const int block = 256;
    long long want = (total + block - 1) / block;
    int grid = (int)(want < 2048 ? want : 2048);

    rope2d_kernel<<<grid, block, 0, stream>>>(x, idx, row_cs, col_cs, out, total);
}